// Round 7
// baseline (313.337 us; speedup 1.0000x reference)
//
#include <hip/hip_runtime.h>

#define DI __device__ __forceinline__

typedef float  f32x2  __attribute__((ext_vector_type(2)));
typedef float  f32x4  __attribute__((ext_vector_type(4)));
typedef float  f32x16 __attribute__((ext_vector_type(16)));
typedef __bf16 bf16x8 __attribute__((ext_vector_type(8)));
typedef unsigned u32x2 __attribute__((ext_vector_type(2)));
typedef unsigned u32x4 __attribute__((ext_vector_type(4)));

static constexpr int TB   = 2048;   // tokens per batch
static constexpr int NTOK = 8192;   // 4 * 2048
static constexpr int EMB  = 1024;
static constexpr int FQKV = 3072;

// RTNE float -> bf16 bits
DI unsigned short f2bf(float f) {
  union { float f; unsigned u; } v; v.f = f;
  unsigned r = v.u + 0x7FFFu + ((v.u >> 16) & 1u);
  return (unsigned short)(r >> 16);
}

// pack two f32 -> two bf16 in one dword: low16 = a, high16 = b
DI unsigned pack2bf(float a, float b) {
#if __has_builtin(__builtin_amdgcn_cvt_pk_bf16_f32)
  typedef __bf16 bf16x2 __attribute__((ext_vector_type(2)));
  bf16x2 r = __builtin_amdgcn_cvt_pk_bf16_f32(a, b);
  return __builtin_bit_cast(unsigned, r);
#else
  unsigned ua = __builtin_bit_cast(unsigned, a) + 0x8000u;  // round-half-up
  unsigned ub = __builtin_bit_cast(unsigned, b) + 0x8000u;
  return __builtin_amdgcn_perm(ub, ua, 0x07060302u);
#endif
}

// v_permlane32_swap: a' = [a.lo32lanes, b.lo32lanes], b' = [a.hi32lanes, b.hi32lanes]
DI void plswap(unsigned& a, unsigned& b) {
#if __has_builtin(__builtin_amdgcn_permlane32_swap)
  u32x2 r = __builtin_amdgcn_permlane32_swap(a, b, false, false);
  a = r.x; b = r.y;
#else
  const bool hi = (threadIdx.x & 32) != 0;
  unsigned ax = (unsigned)__shfl_xor((int)a, 32);
  unsigned bx = (unsigned)__shfl_xor((int)b, 32);
  unsigned na = hi ? bx : a;
  unsigned nb = hi ? b : ax;
  a = na; b = nb;
#endif
}

DI bf16x8 frag4(unsigned a, unsigned b, unsigned c, unsigned d) {
  u32x4 u = {a, b, c, d};
  return __builtin_bit_cast(bf16x8, u);
}

// async global->LDS, 16B per lane; LDS dest = wave-uniform base + lane*16
DI void gload16(const void* g, void* l) {
  __builtin_amdgcn_global_load_lds(
      (__attribute__((address_space(1))) void*)(g),
      (__attribute__((address_space(3))) void*)(l), 16, 0, 0);
}

// barrier with GUARANTEED pre-drain of this wave's outstanding DMA ops
// (r4 post-mortem: compiler may defer the vmcnt wait past s_barrier, making
// another wave read stale LDS; explicit s_waitcnt(0) closes the race).
DI void syncdrain() {
  __builtin_amdgcn_s_waitcnt(0);
  __syncthreads();
}

// s_waitcnt simm16 encodings (gfx9/CDNA): vmcnt[3:0]=simm[3:0],
// expcnt=simm[6:4], lgkmcnt=simm[11:8], vmcnt[5:4]=simm[15:14].
// 0xF74: vmcnt<=4, lgkm/exp don't-care.  0xF70: vmcnt==0, lgkm/exp don't-care.
#define WAITCNT_VM4 0xF74
#define WAITCNT_VM0 0xF70

// ---------------- fp32 -> bf16 conversion for x, w_qkv, w_out ----------------
__global__ __launch_bounds__(256)
void cvt_kernel(const float4* __restrict__ x, const float4* __restrict__ wq,
                const float4* __restrict__ wo,
                ushort4* __restrict__ xb, ushort4* __restrict__ wqb,
                ushort4* __restrict__ wob) {
  const int i  = blockIdx.x * 256 + threadIdx.x;
  const int nx = NTOK * EMB / 4;       // 2097152
  const int nq = FQKV * EMB / 4;       // 786432
  float4 v; ushort4* dst;
  if (i < nx)           { v = x[i];           dst = xb  + i; }
  else if (i < nx + nq) { v = wq[i - nx];     dst = wqb + (i - nx); }
  else                  { v = wo[i - nx - nq]; dst = wob + (i - nx - nq); }
  ushort4 p;
  p.x = f2bf(v.x); p.y = f2bf(v.y); p.z = f2bf(v.z); p.w = f2bf(v.w);
  *dst = p;
}

// ---------------- 128x128 bf16 GEMM, C = A * Bt^T, double-buffered ----------
// r7: double-buffered LDS staging. Per iter: issue prefetch(t+1) FIRST, then
// wait vmcnt<=4 (the 4 FIFO-older DMAs of buf t; each wave issues exactly 4
// per stage), barrier, compute. Prefetch gets a full iteration to land,
// removing the per-iter exposed DMA latency of the single-buffered loop.
// TRANS path (Q/K and MODE1): swapped MFMA operands -> lane = C-row, regs =
// 4 consecutive C-cols -> vectorized stores (r6-verified).
template <int MODE>
__global__ __launch_bounds__(256)
void gemm_bt(const unsigned short* __restrict__ A,
             const unsigned short* __restrict__ Bt,
             const int K,
             unsigned short* __restrict__ qk,
             unsigned short* __restrict__ vT,
             float* __restrict__ outp) {
  __shared__ unsigned short sA[2][128 * 32];
  __shared__ unsigned short sB[2][128 * 32];
  const int tid  = threadIdx.x;
  const int w    = tid >> 6;
  const int l    = tid & 63;
  const int quad = l >> 4;
  const int lr   = l & 15;
  const int n0   = blockIdx.x * 128;
  const int m0   = blockIdx.y * 128;
  const int wm   = (w >> 1) * 64;
  const int wn   = (w & 1) * 64;
  const bool TRANS = (MODE == 1) || (n0 < 2048);

  f32x4 acc[4][4];
#pragma unroll
  for (int i = 0; i < 4; ++i)
#pragma unroll
    for (int j = 0; j < 4; ++j) acc[i][j] = {0.f, 0.f, 0.f, 0.f};

  const int srow = l >> 2;
  const int sg   = (l & 3) ^ ((l >> 3) & 3);
  const unsigned short* gA = A  + (long)(m0 + w * 32 + srow) * K + sg * 8;
  const unsigned short* gB = Bt + (long)(n0 + w * 32 + srow) * K + sg * 8;
  const int swz = (lr >> 1) & 3;

  // prologue: stage k=0 into buf 0
  gload16(gA,          &sA[0][w * 1024]);
  gload16(gA + 16 * K, &sA[0][w * 1024 + 512]);
  gload16(gB,          &sB[0][w * 1024]);
  gload16(gB + 16 * K, &sB[0][w * 1024 + 512]);

  for (int k0 = 0, it = 0; k0 < K; k0 += 32, ++it) {
    const int buf = it & 1;
    if (k0 + 32 < K) {
      const int nb = buf ^ 1;
      gload16(gA + k0 + 32,          &sA[nb][w * 1024]);
      gload16(gA + k0 + 32 + 16 * K, &sA[nb][w * 1024 + 512]);
      gload16(gB + k0 + 32,          &sB[nb][w * 1024]);
      gload16(gB + k0 + 32 + 16 * K, &sB[nb][w * 1024 + 512]);
      __builtin_amdgcn_s_waitcnt(WAITCNT_VM4);  // buf t's 4 DMAs done
    } else {
      __builtin_amdgcn_s_waitcnt(WAITCNT_VM0);  // no prefetch above: drain all
    }
    __syncthreads();
    bf16x8 af[4], bfr[4];
#pragma unroll
    for (int rt = 0; rt < 4; ++rt)
      af[rt] = *(const bf16x8*)(&sA[buf][(wm + rt * 16 + lr) * 32 + (quad ^ swz) * 8]);
#pragma unroll
    for (int ct = 0; ct < 4; ++ct)
      bfr[ct] = *(const bf16x8*)(&sB[buf][(wn + ct * 16 + lr) * 32 + (quad ^ swz) * 8]);
    if (TRANS) {
#pragma unroll
      for (int rt = 0; rt < 4; ++rt)
#pragma unroll
        for (int ct = 0; ct < 4; ++ct)
          acc[rt][ct] = __builtin_amdgcn_mfma_f32_16x16x32_bf16(bfr[ct], af[rt],
                                                                acc[rt][ct], 0, 0, 0);
    } else {
#pragma unroll
      for (int rt = 0; rt < 4; ++rt)
#pragma unroll
        for (int ct = 0; ct < 4; ++ct)
          acc[rt][ct] = __builtin_amdgcn_mfma_f32_16x16x32_bf16(af[rt], bfr[ct],
                                                                acc[rt][ct], 0, 0, 0);
    }
    __syncthreads();  // releases buf for the next iteration's prefetch
  }

  if (MODE == 0) {
    if (n0 < 2048) {
      // TRANS mapping: lane = C-row (m = lr), regs = 4 consecutive cols
      const float qs = (n0 < 1024) ? 0.18033688011112042f : 1.0f;
#pragma unroll
      for (int rt = 0; rt < 4; ++rt) {
        const int row = m0 + wm + rt * 16 + lr;
#pragma unroll
        for (int ct = 0; ct < 4; ++ct) {
          const int col = n0 + wn + ct * 16 + quad * 4;
          ushort4 p;
          p.x = f2bf(acc[rt][ct][0] * qs); p.y = f2bf(acc[rt][ct][1] * qs);
          p.z = f2bf(acc[rt][ct][2] * qs); p.w = f2bf(acc[rt][ct][3] * qs);
          *(ushort4*)(qk + (long)row * 2048 + col) = p;
        }
      }
    } else {
      // V (non-TRANS, r1-verified): regs = 4 consecutive tokens
#pragma unroll
      for (int rt = 0; rt < 4; ++rt) {
        const int tok = m0 + wm + rt * 16 + quad * 4;
        const int bb  = tok >> 11, tt = tok & 2047;
#pragma unroll
        for (int ct = 0; ct < 4; ++ct) {
          const int fv = n0 - 2048 + wn + ct * 16 + lr;  // h*64+d
          ushort4 p;
          p.x = f2bf(acc[rt][ct][0]); p.y = f2bf(acc[rt][ct][1]);
          p.z = f2bf(acc[rt][ct][2]); p.w = f2bf(acc[rt][ct][3]);
          *(ushort4*)(vT + ((long)(bb * 1024 + fv)) * 2048 + tt) = p;
        }
      }
    }
  } else {
    // TRANS fp32 epilogue: float4 stores
#pragma unroll
    for (int rt = 0; rt < 4; ++rt) {
      const int row = m0 + wm + rt * 16 + lr;
#pragma unroll
      for (int ct = 0; ct < 4; ++ct) {
        const int col = n0 + wn + ct * 16 + quad * 4;
        *(f32x4*)(outp + (long)row * 1024 + col) = acc[rt][ct];
      }
    }
  }
}

// ---------------- flash attention (r5-verified version, 104.5 us) -----------
// Block = 256 queries (4 waves x 64q) for one (b,h); grid (bh, qtile) so all
// q-tiles of a (b,h) land on one XCD (linear id % 8 == bh % 8) for K/V L2 reuse.
// K/V staged per 64-key tile via coalesced global_load_lds (double-buffered);
// K-frags and V-frags read once per tile, reused by both 32-q sets.
__global__ __launch_bounds__(256)
void attn_kernel(const unsigned short* __restrict__ qk,
                 const unsigned short* __restrict__ vT,
                 unsigned short* __restrict__ attnb) {
  __shared__ unsigned short sK[2][64 * 64];  // [key][d], 16B-granule swizzled
  __shared__ unsigned short sV[2][64 * 64];  // [d][t],  16B-granule swizzled
  const int tid = threadIdx.x;
  const int w   = tid >> 6;
  const int l   = tid & 63;
  const int l31 = l & 31;
  const int lh  = l >> 5;            // lane half
  const int h8  = lh * 8;            // k-offset of this lane-half in A/B frags
  const int bh  = blockIdx.x;
  const int hh  = bh & 15;
  const long tokbase = (long)(bh >> 4) * TB;
  const int qbase = blockIdx.y * 256 + w * 64;

  // Q fragments (B operand) for both 32-q sets: Q[q][d = s*16 + h8 + j]
  bf16x8 qf[2][4];
#pragma unroll
  for (int qs = 0; qs < 2; ++qs) {
    const unsigned short* qptr =
        qk + (tokbase + qbase + qs * 32 + l31) * 2048 + hh * 64 + h8;
#pragma unroll
    for (int s = 0; s < 4; ++s) qf[qs][s] = *(const bf16x8*)(qptr + s * 16);
  }

  // staging geometry (verified r3): instr covers 8 rows x 8 granules (16B);
  // LDS position spos of row r holds global granule spos ^ (r&7).
  const int srow = l >> 3;
  const int g    = (l & 7) ^ srow;
  const unsigned short* kbase =
      qk + (tokbase + w * 16 + srow) * 2048 + 1024 + hh * 64 + g * 8;
  const unsigned short* vbase =
      vT + ((long)bh * 64 + w * 16 + srow) * 2048 + g * 8;

  f32x16 oacc[2][2] = {{{}, {}}, {{}, {}}};
  f32x2 lp2[2] = {{0.f, 0.f}, {0.f, 0.f}};

  // stage tile 0 into buf 0
  gload16(kbase,            &sK[0][(w * 16 + 0) * 64]);
  gload16(kbase + 8 * 2048, &sK[0][(w * 16 + 8) * 64]);
  gload16(vbase,            &sV[0][(w * 16 + 0) * 64]);
  gload16(vbase + 8 * 2048, &sV[0][(w * 16 + 8) * 64]);
  syncdrain();

  for (int t = 0; t < 32; ++t) {
    const int buf = t & 1;
    if (t + 1 < 32) {
      const int k0 = (t + 1) * 64;
      const int nb = buf ^ 1;
      gload16(kbase + (long)k0 * 2048,            &sK[nb][(w * 16 + 0) * 64]);
      gload16(kbase + (long)k0 * 2048 + 8 * 2048, &sK[nb][(w * 16 + 8) * 64]);
      gload16(vbase + k0,                         &sV[nb][(w * 16 + 0) * 64]);
      gload16(vbase + k0 + 8 * 2048,              &sV[nb][(w * 16 + 8) * 64]);
    }
    const unsigned short* bK = sK[buf];
    const unsigned short* bV = sV[buf];

#pragma unroll
    for (int G = 0; G < 2; ++G) {
      // S^T for both q-sets: A = K rows (32 keys), read once
      f32x16 sacc[2] = {{}, {}};
#pragma unroll
      for (int s = 0; s < 4; ++s) {
        const int key = G * 32 + l31;
        const int p   = (s * 2 + lh) ^ (key & 7);
        const bf16x8 kf = *(const bf16x8*)(bK + key * 64 + p * 8);
        sacc[0] = __builtin_amdgcn_mfma_f32_32x32x16_bf16(kf, qf[0][s], sacc[0], 0, 0, 0);
        sacc[1] = __builtin_amdgcn_mfma_f32_32x32x16_bf16(kf, qf[1][s], sacc[1], 0, 0, 0);
      }
      // softmax numerators + repack to A-frag key order, per q-set
      bf16x8 pp[2][2];
#pragma unroll
      for (int qs = 0; qs < 2; ++qs) {
        float e[16];
#pragma unroll
        for (int i = 0; i < 16; ++i) e[i] = __builtin_amdgcn_exp2f(sacc[qs][i]);
#pragma unroll
        for (int i = 0; i < 8; ++i) {
          f32x2 pr = {e[2 * i], e[2 * i + 1]};
          lp2[qs] += pr;                      // v_pk_add_f32
        }
        unsigned d[8];
#pragma unroll
        for (int i = 0; i < 8; ++i) d[i] = pack2bf(e[2 * i], e[2 * i + 1]);
        plswap(d[0], d[2]); plswap(d[1], d[3]);
        plswap(d[4], d[6]); plswap(d[5], d[7]);
        pp[qs][0] = frag4(d[0], d[1], d[2], d[3]);
        pp[qs][1] = frag4(d[4], d[5], d[6], d[7]);
      }
      // O += P V: V-frags read once per (G,sub), reused by both q-sets
#pragma unroll
      for (int sub = 0; sub < 2; ++sub) {
        const int gt  = (G * 2 + sub) * 2 + lh;
        const int d0r = l31, d1r = 32 + l31;
        const bf16x8 vf0 = *(const bf16x8*)(bV + d0r * 64 + ((gt ^ (d0r & 7))) * 8);
        const bf16x8 vf1 = *(const bf16x8*)(bV + d1r * 64 + ((gt ^ (d1r & 7))) * 8);
#pragma unroll
        for (int qs = 0; qs < 2; ++qs) {
          oacc[qs][0] = __builtin_amdgcn_mfma_f32_32x32x16_bf16(pp[qs][sub], vf0, oacc[qs][0], 0, 0, 0);
          oacc[qs][1] = __builtin_amdgcn_mfma_f32_32x32x16_bf16(pp[qs][sub], vf1, oacc[qs][1], 0, 0, 0);
        }
      }
    }
    syncdrain();
  }

  // normalize per q-set: each lane's lp covers half the keys for q = lane&31
#pragma unroll
  for (int qs = 0; qs < 2; ++qs) {
    const float lp = lp2[qs].x + lp2[qs].y;
    const float fs = lp + __shfl_xor(lp, 32);
    const float rc = 1.0f / fs;
#pragma unroll
    for (int r = 0; r < 16; ++r) {
      const int row = (r & 3) + 8 * (r >> 2) + 4 * lh;  // q within 32-q set
      const float sc = __shfl(rc, row);
      const long base = (tokbase + qbase + qs * 32 + row) * 1024 + hh * 64;
      attnb[base + l31]      = f2bf(oacc[qs][0][r] * sc);
      attnb[base + 32 + l31] = f2bf(oacc[qs][1][r] * sc);
    }
  }
}

// ---------------------------------------------------------------------------
extern "C" void kernel_launch(void* const* d_in, const int* in_sizes, int n_in,
                              void* d_out, int out_size, void* d_ws, size_t ws_size,
                              hipStream_t stream) {
  const float* x    = (const float*)d_in[0];
  const float* wqkv = (const float*)d_in[1];
  const float* wout = (const float*)d_in[2];
  float* outp = (float*)d_out;

  unsigned short* xb    = (unsigned short*)d_ws;          // 8192*1024
  unsigned short* wqkvb = xb    + (long)NTOK * EMB;       // 3072*1024
  unsigned short* woutb = wqkvb + (long)FQKV * EMB;       // 1024*1024
  unsigned short* qkb   = woutb + (long)EMB * EMB;        // 8192*2048 (Q|K)
  unsigned short* vTb   = qkb   + (long)NTOK * 2048;      // 4*16*64*2048
  unsigned short* attnb = vTb   + (long)4 * 16 * 64 * TB; // 8192*1024

  cvt_kernel<<<12288, 256, 0, stream>>>(
      (const float4*)x, (const float4*)wqkv, (const float4*)wout,
      (ushort4*)xb, (ushort4*)wqkvb, (ushort4*)woutb);

  gemm_bt<0><<<dim3(24, 64), 256, 0, stream>>>(xb, wqkvb, EMB, qkb, vTb, nullptr);

  // attention: grid (bh, qtile) -> XCD-local K/V reuse
  attn_kernel<<<dim3(64, 8), 256, 0, stream>>>(qkb, vTb, attnb);

  gemm_bt<1><<<dim3(8, 64), 256, 0, stream>>>(attnb, woutb, EMB, nullptr, nullptr, outp);
}